// Round 8
// baseline (536.070 us; speedup 1.0000x reference)
//
#include <hip/hip_runtime.h>
#include <hip/hip_bf16.h>
#include <stdint.h>

#define DM 1024
#define NH 16
#define HD 64
#define SEQ 2048
#define NB 2
#define NC 2            // attn2 k-split (partial X chunks)

typedef __attribute__((ext_vector_type(8)))  __bf16 bf16x8;
typedef __attribute__((ext_vector_type(4)))  __bf16 bf16x4;
typedef __attribute__((ext_vector_type(4)))  float  f32x4;
typedef __attribute__((ext_vector_type(16))) float  f32x16;
typedef __attribute__((ext_vector_type(4)))  unsigned int uint4v;
typedef __attribute__((ext_vector_type(4)))  int    i32x4;

__device__ __forceinline__ f32x16 mfma32x32(bf16x8 a, bf16x8 b, f32x16 c) {
  return __builtin_amdgcn_mfma_f32_32x32x16_bf16(a, b, c, 0, 0, 0);
}
__device__ __forceinline__ f32x4 mfma16x16(bf16x8 a, bf16x8 b, f32x4 c) {
  return __builtin_amdgcn_mfma_f32_16x16x32_bf16(a, b, c, 0, 0, 0);
}
__device__ __forceinline__ unsigned pkbf(float a, float b) {
  unsigned short ua = __builtin_bit_cast(unsigned short, (__bf16)a);
  unsigned short ub = __builtin_bit_cast(unsigned short, (__bf16)b);
  return (unsigned)ua | ((unsigned)ub << 16);
}
__device__ __forceinline__ f32x16 zero16() {
  f32x16 z;
#pragma unroll
  for (int i = 0; i < 16; i++) z[i] = 0.0f;
  return z;
}

// ---------------- W transpose + bf16 convert ------------------------------
// Wt slot order: 0=Wo, 1=Wq, 2=Wk, 3=Wv  (Wo first so Wq slot can be
// recycled as mbit storage after qkv has consumed it — stream-ordered).
__global__ void wconv_kernel(const float* __restrict__ Wq, const float* __restrict__ Wk,
                             const float* __restrict__ Wv, const float* __restrict__ Wo,
                             __bf16* __restrict__ Wt) {
  __shared__ float tile[32][33];
  const int which = blockIdx.z;
  const float* W = (which == 0) ? Wq : (which == 1) ? Wk : (which == 2) ? Wv : Wo;
  __bf16* out = Wt + (size_t)((which + 1) & 3) * DM * DM;
  const int n0 = blockIdx.x * 32, k0 = blockIdx.y * 32;
  const int tx = threadIdx.x & 31, ty = threadIdx.x >> 5;  // ty 0..7
#pragma unroll
  for (int i = 0; i < 4; i++) {
    tile[ty + i * 8][tx] = W[(size_t)(k0 + ty + i * 8) * DM + n0 + tx];
  }
  __syncthreads();
#pragma unroll
  for (int i = 0; i < 4; i++) {
    out[(size_t)(n0 + ty + i * 8) * DM + k0 + tx] = (__bf16)tile[tx][ty + i * 8];
  }
}

// ---------------- Fused QKV projection GEMM (128x128 tile, z selects Q/K/V) --
__global__ __launch_bounds__(256, 3)
void qkv_kernel(const float* __restrict__ Aq, const float* __restrict__ Ak,
                const float* __restrict__ Av, const __bf16* __restrict__ Wt,
                const float* __restrict__ bqv, const float* __restrict__ bkv,
                const float* __restrict__ bvv, __bf16* __restrict__ Qh,
                __bf16* __restrict__ Kh, __bf16* __restrict__ Vt) {
  __shared__ __bf16 Alds[128][40];
  __shared__ __bf16 Blds[128][40];
  const int z = blockIdx.z;
  const float* A = (z == 0) ? Aq : (z == 1) ? Ak : Av;
  const __bf16* Bt = Wt + (size_t)(z + 1) * DM * DM;  // slots 1,2,3
  const float* bias = (z == 0) ? bqv : (z == 1) ? bkv : bvv;

  const int tid = threadIdx.x;
  const int l = tid & 63, w = tid >> 6;
  const int wm = w >> 1, wn = w & 1;
  const int r0 = blockIdx.x * 128, c0 = blockIdx.y * 128;

  f32x4 acc[4][4];
#pragma unroll
  for (int m = 0; m < 4; m++)
#pragma unroll
    for (int n = 0; n < 4; n++)
#pragma unroll
      for (int r = 0; r < 4; r++) acc[m][n][r] = 0.0f;

  const int ar = tid >> 2;  // 0..63 (two rows: ar, ar+64)
  const int aq = tid & 3;
  const int br = tid >> 1;  // 0..127
  const int bh = tid & 1;

  for (int kt = 0; kt < DM / 32; kt++) {
#pragma unroll
    for (int rep = 0; rep < 2; rep++) {
      const int row = ar + rep * 64;
      const float* src = A + (size_t)(r0 + row) * DM + kt * 32 + aq * 8;
      const f32x4 v0 = *(const f32x4*)(src);
      const f32x4 v1 = *(const f32x4*)(src + 4);
      bf16x8 av;
#pragma unroll
      for (int i = 0; i < 4; i++) { av[i] = (__bf16)v0[i]; av[4 + i] = (__bf16)v1[i]; }
      *(bf16x8*)&Alds[row][aq * 8] = av;
    }
    {
      const __bf16* bsrc = Bt + (size_t)(c0 + br) * DM + kt * 32 + bh * 16;
      bf16x8 v0 = *(const bf16x8*)bsrc;
      bf16x8 v1 = *(const bf16x8*)(bsrc + 8);
      *(bf16x8*)&Blds[br][bh * 16] = v0;
      *(bf16x8*)&Blds[br][bh * 16 + 8] = v1;
    }
    __syncthreads();
    bf16x8 af[4], bfr[4];
#pragma unroll
    for (int m = 0; m < 4; m++)
      af[m] = *(const bf16x8*)&Alds[wm * 64 + m * 16 + (l & 15)][(l >> 4) * 8];
#pragma unroll
    for (int n = 0; n < 4; n++)
      bfr[n] = *(const bf16x8*)&Blds[wn * 64 + n * 16 + (l & 15)][(l >> 4) * 8];
#pragma unroll
    for (int m = 0; m < 4; m++)
#pragma unroll
      for (int n = 0; n < 4; n++) acc[m][n] = mfma16x16(af[m], bfr[n], acc[m][n]);
    __syncthreads();
  }

  const int ccol = l & 15;
  const int crb = (l >> 4) * 4;
  __bf16* Ohm = (z == 0) ? Qh : Kh;
#pragma unroll
  for (int n = 0; n < 4; n++) {
    const int col = c0 + wn * 64 + n * 16 + ccol;
    const float bv = bias[col];
    const int h = col >> 6, d = col & 63;
#pragma unroll
    for (int m = 0; m < 4; m++) {
      const int row = r0 + wm * 64 + m * 16 + crb;
      f32x4 v = acc[m][n];
#pragma unroll
      for (int r = 0; r < 4; r++) v[r] += bv;
      if (z < 2) {  // head-major [b,h,l,d]
#pragma unroll
        for (int r = 0; r < 4; r++) {
          const int rr = row + r; const int bb = rr >> 11; const int ll = rr & 2047;
          Ohm[(((size_t)bb * NH + h) * SEQ + ll) * HD + d] = (__bf16)v[r];
        }
      } else {  // V^T [b,h,d,l]
        const int bb = row >> 11, ll = row & 2047;
        bf16x4 pk;
#pragma unroll
        for (int r = 0; r < 4; r++) pk[r] = (__bf16)v[r];
        *(bf16x4*)&Vt[(((size_t)bb * NH + h) * HD + d) * SEQ + ll] = pk;
      }
    }
  }
}

// ---------------- Pass A: denominators over the HEADS axis -----------------
// One wave = one 32q x 32k tile, loops all 16 heads. No LDS, no barriers.
// E' = mfma(K, Q): col = q_local = l&31, row = k_local = (r&3)+8*(r>>2)+4*hi
// Stores Dinv (bf16, [b][q][k] row-major!) and bit-packed mask mbit[b][q][k/32].
__global__ __launch_bounds__(512, 4)
void denom_kernel(const __bf16* __restrict__ Qh, const __bf16* __restrict__ Kh,
                  const int* __restrict__ mask, __bf16* __restrict__ Dinv,
                  unsigned* __restrict__ mbit) {
  const int tid = threadIdx.x;
  const int l = tid & 63, w = tid >> 6;
  const int lq = l & 31, hi = l >> 5;
  const int ktg = blockIdx.x;            // 8  (XCD k-chunk affinity)
  const int b = blockIdx.y;              // 2
  const int qt = blockIdx.z;             // 64
  const int q0 = qt * 32;
  const int k0 = (ktg * 8 + w) * 32;     // wave's 32-k tile

  // Build mask word for this lane's q-row over [k0, k0+32)
  unsigned word = 0;
  {
    const i32x4* mp = (const i32x4*)(mask + ((size_t)b * SEQ + q0 + lq) * SEQ + k0);
#pragma unroll
    for (int j = 0; j < 8; j++) {
      const i32x4 v = mp[j];
      word |= (v.x ? 1u : 0u) << (4 * j);
      word |= (v.y ? 1u : 0u) << (4 * j + 1);
      word |= (v.z ? 1u : 0u) << (4 * j + 2);
      word |= (v.w ? 1u : 0u) << (4 * j + 3);
    }
    if (hi == 0) mbit[((size_t)b * SEQ + q0 + lq) * (SEQ / 32) + (k0 >> 5)] = word;
  }

  float dsum[16];
#pragma unroll
  for (int r = 0; r < 16; r++) dsum[r] = 0.0f;

  const __bf16* qbase = Qh + ((size_t)b * NH) * SEQ * HD + (size_t)(q0 + lq) * HD + hi * 8;
  const __bf16* kbase = Kh + ((size_t)b * NH) * SEQ * HD + (size_t)(k0 + lq) * HD + hi * 8;

  for (int h = 0; h < NH; h++) {
    const __bf16* qp = qbase + (size_t)h * SEQ * HD;
    const __bf16* kp = kbase + (size_t)h * SEQ * HD;
    bf16x8 qf[4], kf[4];
#pragma unroll
    for (int ch = 0; ch < 4; ch++) {
      qf[ch] = *(const bf16x8*)(qp + ch * 16);
      kf[ch] = *(const bf16x8*)(kp + ch * 16);
    }
    f32x16 e = zero16();
#pragma unroll
    for (int ch = 0; ch < 4; ch++) e = mfma32x32(kf[ch], qf[ch], e);
#pragma unroll
    for (int r = 0; r < 16; r++) {
      const int crow = (r & 3) + 8 * (r >> 2) + 4 * hi;
      const float bv = ((word >> crow) & 1u) ? 0.0f : -1e10f;
      dsum[r] += __expf(fmaf(e[r], 0.125f, bv));
    }
  }
  // Store reciprocal, row-major [b][q][k]: 4x 8B stores per lane.
  // r = g*4+j -> k_local = j + 8g + 4hi  (j consecutive)
  const size_t qrow = ((size_t)b * SEQ + q0 + lq) * SEQ;
#pragma unroll
  for (int g = 0; g < 4; g++) {
    bf16x4 pk;
#pragma unroll
    for (int j = 0; j < 4; j++)
      pk[j] = (__bf16)__builtin_amdgcn_rcpf(dsum[g * 4 + j]);
    *(bf16x4*)&Dinv[qrow + k0 + 8 * g + 4 * hi] = pk;
  }
}

// ---------------- Pass B: per-head attention, barrier-free, k-split ---------
// One wave = 32 q-rows of one head, sweeps SEQ/NC k. No LDS, no barriers.
__global__ __launch_bounds__(256, 4)
void attn2_kernel(const __bf16* __restrict__ Qh, const __bf16* __restrict__ Kh,
                  const __bf16* __restrict__ Vt, const __bf16* __restrict__ Dinv,
                  const unsigned* __restrict__ mbit, __bf16* __restrict__ Xp) {
  const int tid = threadIdx.x;
  const int l = tid & 63, w = tid >> 6;  // 4 waves
  const int lq = l & 31, hi = l >> 5;
  const int bh = blockIdx.x;             // 32 (head XCD affinity)
  const int b = bh >> 4;
  const int q0 = (blockIdx.y * 4 + w) * 32;  // grid.y = 16
  const int c = blockIdx.z;              // NC k-chunks

  bf16x8 qf[4];
  {
    const __bf16* qp = Qh + ((size_t)bh * SEQ + q0 + lq) * HD + hi * 8;
#pragma unroll
    for (int ch = 0; ch < 4; ch++) qf[ch] = *(const bf16x8*)(qp + ch * 16);
  }
  f32x16 x0 = zero16(), x1 = zero16();

  const __bf16* kbase = Kh + (size_t)bh * SEQ * HD;
  const __bf16* vbase = Vt + (size_t)bh * HD * SEQ;
  const unsigned* mrow = mbit + ((size_t)b * SEQ + q0 + lq) * (SEQ / 32);
  const __bf16* drow = Dinv + ((size_t)b * SEQ + q0 + lq) * SEQ;  // + k

  for (int kt = c * (SEQ / 32 / NC); kt < (c + 1) * (SEQ / 32 / NC); kt++) {
    const int k0 = kt * 32;
    f32x16 e = zero16();
#pragma unroll
    for (int ch = 0; ch < 4; ch++) {
      const bf16x8 kf = *(const bf16x8*)(kbase + (size_t)(k0 + lq) * HD + ch * 16 + hi * 8);
      e = mfma32x32(kf, qf[ch], e);
    }
    // Dinv row: 32 consecutive k as 4 vector loads (was 16 scalar gathers)
    bf16x8 dv[4];
#pragma unroll
    for (int g = 0; g < 4; g++) dv[g] = *(const bf16x8*)(drow + k0 + 8 * g);
    const unsigned word = mrow[kt];
    float p[16], rd[16];
#pragma unroll
    for (int r = 0; r < 16; r++) {
      const int j = r & 3, g = r >> 2;
      const int crow = j + 8 * g + 4 * hi;
      const float bv = ((word >> crow) & 1u) ? 0.0f : -1e10f;
      p[r] = __expf(fmaf(e[r], 0.125f, bv));
      const float rlo = (float)dv[g][j];
      const float rhi = (float)dv[g][j + 4];
      rd[r] = hi ? rhi : rlo;
    }
    unsigned u[8];
#pragma unroll
    for (int j = 0; j < 8; j++) {
      const float a = p[2 * j] * rd[2 * j];
      const float bb2 = p[2 * j + 1] * rd[2 * j + 1];
      u[j] = pkbf(a, bb2);
    }
    unsigned t[8];
#pragma unroll
    for (int j = 0; j < 8; j++) t[j] = (unsigned)__shfl_xor((int)u[j], 32, 64);
    const unsigned w0 = hi ? t[2] : u[0];
    const unsigned w1 = hi ? t[3] : u[1];
    const unsigned w2 = hi ? u[2] : t[0];
    const unsigned w3 = hi ? u[3] : t[1];
    const unsigned w4 = hi ? t[6] : u[4];
    const unsigned w5 = hi ? t[7] : u[5];
    const unsigned w6 = hi ? u[6] : t[4];
    const unsigned w7 = hi ? u[7] : t[5];
    const uint4v s0v = {w0, w1, w2, w3};
    const uint4v s1v = {w4, w5, w6, w7};
    const bf16x8 pa0 = __builtin_bit_cast(bf16x8, s0v);
    const bf16x8 pa1 = __builtin_bit_cast(bf16x8, s1v);
    const __bf16* vp = vbase + (size_t)lq * SEQ + k0 + hi * 8;
    bf16x8 vf;
    vf = *(const bf16x8*)(vp);                         x0 = mfma32x32(pa0, vf, x0);
    vf = *(const bf16x8*)(vp + 16);                    x0 = mfma32x32(pa1, vf, x0);
    vf = *(const bf16x8*)(vp + (size_t)32 * SEQ);      x1 = mfma32x32(pa0, vf, x1);
    vf = *(const bf16x8*)(vp + (size_t)32 * SEQ + 16); x1 = mfma32x32(pa1, vf, x1);
  }

  // Write partial X (bf16): Xp[c][b][h][q][d]
  const size_t XCH = (size_t)NB * NH * SEQ * HD;
  __bf16* xo = Xp + (size_t)c * XCH + ((size_t)bh * SEQ + q0) * HD;
#pragma unroll
  for (int dt = 0; dt < 2; dt++) {
    const f32x16& xx = dt ? x1 : x0;
#pragma unroll
    for (int r = 0; r < 16; r++) {
      const int crow = (r & 3) + 8 * (r >> 2) + 4 * hi;
      xo[(size_t)crow * HD + dt * 32 + lq] = (__bf16)xx[r];
    }
  }
}

// ---------------- O-GEMM: Out = (sum_c Xp_c)[head-major] @ WoT + bo ---------
__global__ __launch_bounds__(256, 4)
void ogemm_kernel(const __bf16* __restrict__ Xp, const __bf16* __restrict__ Bt,
                  const float* __restrict__ bias, float* __restrict__ Out) {
  __shared__ __bf16 Alds[64][40];
  __shared__ __bf16 Blds[128][40];
  const int tid = threadIdx.x;
  const int l = tid & 63, w = tid >> 6;  // w -> n-offset w*32
  const int r0 = blockIdx.x * 64, c0 = blockIdx.y * 128;

  f32x4 acc[4][2];
#pragma unroll
  for (int m = 0; m < 4; m++)
#pragma unroll
    for (int n = 0; n < 2; n++)
#pragma unroll
      for (int r = 0; r < 4; r++) acc[m][n][r] = 0.0f;

  const int ar = tid >> 2, aq = tid & 3;
  const int br = tid >> 1, bh = tid & 1;
  const size_t PART = (size_t)NB * NH * SEQ * HD;
  const int rr = r0 + ar;
  const int bb = rr >> 11, ll = rr & 2047;

  for (int kt = 0; kt < DM / 32; kt++) {
    {
      const int cc = kt * 32 + aq * 8;
      const int h = cc >> 6, d = cc & 63;
      const size_t off = (((size_t)bb * NH + h) * SEQ + ll) * HD + d;
      float fv[8];
#pragma unroll
      for (int i = 0; i < 8; i++) fv[i] = 0.0f;
#pragma unroll
      for (int c = 0; c < NC; c++) {
        const bf16x8 v = *(const bf16x8*)(Xp + (size_t)c * PART + off);
#pragma unroll
        for (int i = 0; i < 8; i++) fv[i] += (float)v[i];
      }
      bf16x8 av;
#pragma unroll
      for (int i = 0; i < 8; i++) av[i] = (__bf16)fv[i];
      *(bf16x8*)&Alds[ar][aq * 8] = av;
    }
    {
      const __bf16* bsrc = Bt + (size_t)(c0 + br) * DM + kt * 32 + bh * 16;
      bf16x8 v0 = *(const bf16x8*)bsrc;
      bf16x8 v1 = *(const bf16x8*)(bsrc + 8);
      *(bf16x8*)&Blds[br][bh * 16] = v0;
      *(bf16x8*)&Blds[br][bh * 16 + 8] = v1;
    }
    __syncthreads();
    bf16x8 af[4], bfr[2];
#pragma unroll
    for (int m = 0; m < 4; m++)
      af[m] = *(const bf16x8*)&Alds[m * 16 + (l & 15)][(l >> 4) * 8];
#pragma unroll
    for (int n = 0; n < 2; n++)
      bfr[n] = *(const bf16x8*)&Blds[w * 32 + n * 16 + (l & 15)][(l >> 4) * 8];
#pragma unroll
    for (int m = 0; m < 4; m++)
#pragma unroll
      for (int n = 0; n < 2; n++) acc[m][n] = mfma16x16(af[m], bfr[n], acc[m][n]);
    __syncthreads();
  }

  const int ccol = l & 15;
  const int crb = (l >> 4) * 4;
#pragma unroll
  for (int n = 0; n < 2; n++) {
    const int col = c0 + w * 32 + n * 16 + ccol;
    const float bv = bias[col];
#pragma unroll
    for (int m = 0; m < 4; m++) {
      const int row = r0 + m * 16 + crb;
      f32x4 v = acc[m][n];
#pragma unroll
      for (int r = 0; r < 4; r++) Out[(size_t)(row + r) * DM + col] = v[r] + bv;
    }
  }
}

// ---------------------------------------------------------------------------
// Workspace (64 MiB exactly):
//   [ 0, 8)  Wt  slots: 0=Wo, 1=Wq, 2=Wk, 3=Wv
//            mbit (1 MiB) overlaps slot 1 (Wq) at +2 MiB — written by denom
//            AFTER qkv consumed Wq (stream-ordered, safe).
//   [ 8,16)  Qh   [b,h,l,d] bf16
//   [16,24)  Kh   [b,h,l,d] bf16
//   [24,32)  Vt   [b,h,d,l] bf16
//   [32,48)  Xp   NC=2 chunks of [b,h,q,d] bf16
//   [48,64)  Dinv [b][q][k]  bf16
extern "C" void kernel_launch(void* const* d_in, const int* in_sizes, int n_in,
                              void* d_out, int out_size, void* d_ws, size_t ws_size,
                              hipStream_t stream) {
  const float* q = (const float*)d_in[0];
  const float* k = (const float*)d_in[1];
  const float* v = (const float*)d_in[2];
  const int* msk = (const int*)d_in[3];
  const float* Wq = (const float*)d_in[4];
  const float* bq = (const float*)d_in[5];
  const float* Wk = (const float*)d_in[6];
  const float* bk = (const float*)d_in[7];
  const float* Wv = (const float*)d_in[8];
  const float* bv = (const float*)d_in[9];
  const float* Wo = (const float*)d_in[10];
  const float* bo = (const float*)d_in[11];

  char* ws = (char*)d_ws;
  const size_t MB = 1024 * 1024;
  if (ws_size < 64 * MB) return;  // visible failure rather than OOB
  __bf16* Wt = (__bf16*)(ws);                  // 8 MiB, slots above
  unsigned* mbit = (unsigned*)(ws + 2 * MB);   // 1 MiB, overlaps retired Wq slot
  __bf16* Qh = (__bf16*)(ws + 8 * MB);
  __bf16* Kh = (__bf16*)(ws + 16 * MB);
  __bf16* Vt = (__bf16*)(ws + 24 * MB);
  __bf16* Xp = (__bf16*)(ws + 32 * MB);        // 2 x 8 MiB
  __bf16* Dinv = (__bf16*)(ws + 48 * MB);      // 16 MiB

  wconv_kernel<<<dim3(32, 32, 4), 256, 0, stream>>>(Wq, Wk, Wv, Wo, Wt);
  qkv_kernel<<<dim3(32, 8, 3), 256, 0, stream>>>(q, k, v, Wt, bq, bk, bv, Qh, Kh, Vt);
  denom_kernel<<<dim3(8, 2, 64), 512, 0, stream>>>(Qh, Kh, msk, Dinv, mbit);
  attn2_kernel<<<dim3(32, 16, NC), 256, 0, stream>>>(Qh, Kh, Vt, Dinv, mbit, Xp);
  ogemm_kernel<<<dim3(64, 8), 256, 0, stream>>>(Xp, Wt, bo, (float*)d_out);
}